// Round 2
// baseline (706.636 us; speedup 1.0000x reference)
//
#include <hip/hip_runtime.h>

// RobustContrastNormalization on [256, 384, 384, 3] fp32.
// Histogram-based quantile (8192 bins over [0,1]) instead of sort.
// Quantile error <= bin width (1.2e-4) -> output error ~5e-4 << 2e-2 threshold.
//
// R1 fix: stats/xg workspace overlap corrupted the first 448 xg elements
// (absmax exactly 1.0). hist + stats now live in module __device__ globals;
// d_ws holds only the optional xg staging buffer.

#define NBINS   8192
#define NPIX    (384 * 384)   // 147456 pixels per sample
#define NSAMP   256
#define HBPS    8             // hist kernel: blocks per sample
#define NBPS    16            // norm kernel: blocks per sample

// Ranks for jnp.quantile linear interpolation, N = 147456:
//   q=0.1: pos = 0.1*(N-1) = 14745.5  -> avg of sorted[14745], sorted[14746]
//   q=0.9: pos = 0.9*(N-1) = 132709.5 -> avg of sorted[132709], sorted[132710]

__device__ unsigned int g_hist[NSAMP * NBINS];   // 8 MB module memory
__device__ float        g_stats[NSAMP * 2];      // lo, 1/rng per sample

__global__ __launch_bounds__(256) void zero_kernel() {
    // NSAMP*NBINS = 2097152 uints = 524288 uint4; grid 2048 x 256 covers it.
    uint4* p = (uint4*)g_hist;
    p[blockIdx.x * 256 + threadIdx.x] = make_uint4(0u, 0u, 0u, 0u);
}

__global__ __launch_bounds__(256) void hist_kernel(const float* __restrict__ x,
                                                   float* __restrict__ xg,
                                                   int writeXg) {
    __shared__ unsigned int lhist[NBINS];
    for (int i = threadIdx.x; i < NBINS; i += 256) lhist[i] = 0u;
    __syncthreads();

    const int s  = blockIdx.x / HBPS;
    const int bs = blockIdx.x % HBPS;
    const int pixPerBlock = NPIX / HBPS;             // 18432
    const long long pixBase = (long long)s * NPIX + (long long)bs * pixPerBlock;
    const float* xp = x + pixBase * 3;
    float* xgp = xg + pixBase;

    // 256 threads * 4 pixels/thread = 1024 pixels per iteration -> 18 iters.
    for (int it = 0; it < pixPerBlock / 1024; ++it) {
        const int p = it * 1024 + threadIdx.x * 4;   // pixel offset in chunk
        const float4* v = (const float4*)(xp + (long long)p * 3);
        float4 a = v[0], b = v[1], c = v[2];
        const float k3 = 1.0f / 3.0f;
        float m0 = (a.x + a.y + a.z) * k3;
        float m1 = (a.w + b.x + b.y) * k3;
        float m2 = (b.z + b.w + c.x) * k3;
        float m3 = (c.y + c.z + c.w) * k3;
        int i0 = min(NBINS - 1, max(0, (int)(m0 * (float)NBINS)));
        int i1 = min(NBINS - 1, max(0, (int)(m1 * (float)NBINS)));
        int i2 = min(NBINS - 1, max(0, (int)(m2 * (float)NBINS)));
        int i3 = min(NBINS - 1, max(0, (int)(m3 * (float)NBINS)));
        atomicAdd(&lhist[i0], 1u);
        atomicAdd(&lhist[i1], 1u);
        atomicAdd(&lhist[i2], 1u);
        atomicAdd(&lhist[i3], 1u);
        if (writeXg) {
            *(float4*)(xgp + p) = make_float4(m0, m1, m2, m3);
        }
    }
    __syncthreads();

    unsigned int* gh = g_hist + (size_t)s * NBINS;
    for (int i = threadIdx.x; i < NBINS; i += 256) {
        unsigned int cnt = lhist[i];
        if (cnt) atomicAdd(&gh[i], cnt);
    }
}

__global__ __launch_bounds__(256) void quant_kernel() {
    const int s = blockIdx.x;
    const unsigned int* gh = g_hist + (size_t)s * NBINS;

    __shared__ unsigned int lbh[NBINS];
    __shared__ unsigned int tsum[256];
    __shared__ float results[4];

    for (int i = threadIdx.x; i < NBINS; i += 256) lbh[i] = gh[i];
    __syncthreads();

    const int PER  = NBINS / 256;  // 32 bins per thread
    const int base = threadIdx.x * PER;
    unsigned int tot = 0;
    for (int i = 0; i < PER; ++i) tot += lbh[base + i];
    tsum[threadIdx.x] = tot;
    __syncthreads();

    if (threadIdx.x == 0) {
        unsigned int run = 0;
        for (int i = 0; i < 256; ++i) { unsigned int t = tsum[i]; tsum[i] = run; run += t; }
    }
    __syncthreads();

    unsigned int cum = tsum[threadIdx.x];
    const unsigned int ranks[4] = {14745u, 14746u, 132709u, 132710u};
    for (int i = 0; i < PER; ++i) {
        unsigned int c = lbh[base + i];
        if (c) {
            for (int r = 0; r < 4; ++r) {
                unsigned int k = ranks[r];
                if (k >= cum && k < cum + c) {
                    float frac = ((float)(k - cum) + 0.5f) / (float)c;
                    results[r] = ((float)(base + i) + frac) * (1.0f / (float)NBINS);
                }
            }
            cum += c;
        }
    }
    __syncthreads();

    if (threadIdx.x == 0) {
        float lo  = 0.5f * (results[0] + results[1]);
        float hi  = 0.5f * (results[2] + results[3]);
        float rng = fmaxf(hi - lo, 1e-6f);
        g_stats[s * 2 + 0] = lo;
        g_stats[s * 2 + 1] = 1.0f / rng;
    }
}

__global__ __launch_bounds__(256) void norm_kernel(const float* __restrict__ src,
                                                   float* __restrict__ out,
                                                   int channels) {
    const int s  = blockIdx.x / NBPS;
    const int bs = blockIdx.x % NBPS;
    const int pixPerBlock = NPIX / NBPS;             // 9216
    const float lo   = g_stats[s * 2 + 0];
    const float rinv = g_stats[s * 2 + 1];
    const long long pixBase = (long long)s * NPIX + (long long)bs * pixPerBlock;
    float* op = out + pixBase;

    if (channels == 3) {
        const float* xp = src + pixBase * 3;
        const float k3 = 1.0f / 3.0f;
        for (int it = 0; it < pixPerBlock / 1024; ++it) {
            const int p = it * 1024 + threadIdx.x * 4;
            const float4* v = (const float4*)(xp + (long long)p * 3);
            float4 a = v[0], b = v[1], c = v[2];
            float m0 = (a.x + a.y + a.z) * k3;
            float m1 = (a.w + b.x + b.y) * k3;
            float m2 = (b.z + b.w + c.x) * k3;
            float m3 = (c.y + c.z + c.w) * k3;
            float4 o;
            o.x = fminf(fmaxf((m0 - lo) * rinv, 0.0f), 1.0f);
            o.y = fminf(fmaxf((m1 - lo) * rinv, 0.0f), 1.0f);
            o.z = fminf(fmaxf((m2 - lo) * rinv, 0.0f), 1.0f);
            o.w = fminf(fmaxf((m3 - lo) * rinv, 0.0f), 1.0f);
            *(float4*)(op + p) = o;
        }
    } else {
        const float* xp = src + pixBase;
        for (int it = 0; it < pixPerBlock / 1024; ++it) {
            const int p = it * 1024 + threadIdx.x * 4;
            float4 m = *(const float4*)(xp + p);
            float4 o;
            o.x = fminf(fmaxf((m.x - lo) * rinv, 0.0f), 1.0f);
            o.y = fminf(fmaxf((m.y - lo) * rinv, 0.0f), 1.0f);
            o.z = fminf(fmaxf((m.z - lo) * rinv, 0.0f), 1.0f);
            o.w = fminf(fmaxf((m.w - lo) * rinv, 0.0f), 1.0f);
            *(float4*)(op + p) = o;
        }
    }
}

extern "C" void kernel_launch(void* const* d_in, const int* in_sizes, int n_in,
                              void* d_out, int out_size, void* d_ws, size_t ws_size,
                              hipStream_t stream) {
    const float* x = (const float*)d_in[0];
    float* out = (float*)d_out;

    const size_t xgBytes = (size_t)NSAMP * NPIX * sizeof(float);   // 151 MB
    float* xg = (float*)d_ws;
    const int useXg = (ws_size >= xgBytes) ? 1 : 0;

    zero_kernel<<<(NSAMP * NBINS / 4) / 256, 256, 0, stream>>>();
    hist_kernel<<<NSAMP * HBPS, 256, 0, stream>>>(x, xg, useXg);
    quant_kernel<<<NSAMP, 256, 0, stream>>>();
    norm_kernel<<<NSAMP * NBPS, 256, 0, stream>>>(useXg ? (const float*)xg : x,
                                                  out, useXg ? 1 : 3);
}